// Round 9
// baseline (376.501 us; speedup 1.0000x reference)
//
#include <hip/hip_runtime.h>
#include <hip/hip_bf16.h>

// FusedColorMLP: out = relu(relu(enc @ W1) @ W2) @ W3
// enc = [SH-deg4(x[:, :3]) (16) | x[:, 3:19] (16)]  -> 32 features
// bf16 MFMA (16x16x32), fp32 accumulate. One wave = 16 points/iter.
// R9 change: target VGPR <= 64 (occupancy cliff per m68/m69: 68 VGPRs
// allocates the 128-quantum -> 4 waves/SIMD; <=64 -> 8 waves/SIMD).
//   - int32 indexing everywhere (all offsets < 2^31)
//   - W3 B-fragment demoted from 8 persistent VGPRs to a 2KB LDS table,
//     re-read per iteration (opaque-ptr asm defeats LICM re-hoisting)
//   - __launch_bounds__(256, 8) pins the allocator
// R8 post-mortem: 64-thread blocks hit the ~16 wg/CU cap (16 waves/CU),
// WORSE than R7's 32 waves/CU. Residency, not barrier coupling, is the
// bottleneck (VALU 38-43%, MFMA 9-10%, HBM 10-12%: nothing saturated).

typedef short short8 __attribute__((ext_vector_type(8)));
typedef short short4v __attribute__((ext_vector_type(4)));
typedef float f32x4 __attribute__((ext_vector_type(4)));

#define MFMA16(a, b, c) __builtin_amdgcn_mfma_f32_16x16x32_bf16((a), (b), (c), 0, 0, 0)

static __device__ __forceinline__ short f2bf(float f) {
  __hip_bfloat16 h = __float2bfloat16(f);  // RNE
  return __builtin_bit_cast(short, h);
}

#define LDS_PAD 68   // row stride in bf16 elems: 136B
#define ITERS 16     // 16 points/iter -> 256 points per wave

__global__ __launch_bounds__(256, 8) void fused_color_mlp(
    const float* __restrict__ x, const float* __restrict__ W1,
    const float* __restrict__ W2, const float* __restrict__ W3,
    float* __restrict__ out, int N) {
  __shared__ short h1s[4][16][LDS_PAD];
  __shared__ short h2s[4][16][LDS_PAD];
  __shared__ short w3f[64][16];  // per-lane W3 B-fragment table (2KB)

  const int tid = threadIdx.x;
  const int wv = tid >> 6;      // wave in block
  const int lane = tid & 63;
  const int row = lane & 15;    // A row / B,C col
  const int kg = lane >> 4;     // k-group (8 consecutive k per lane)

  // ---- one-time: W3 (64x3, zero-padded to 16 cols) fragment -> LDS ----
  if (tid < 64) {
    const int c3r = (row < 3) ? row : 2;  // clamped: speculation-safe
#pragma unroll
    for (int s = 0; s < 2; ++s)
#pragma unroll
      for (int j = 0; j < 8; ++j) {
        short w = f2bf(W3[(s * 32 + kg * 8 + j) * 3 + c3r]);
        w3f[lane][s * 8 + j] = (row < 3) ? w : (short)0;
      }
  }

  // ---- one-time: W1/W2 B-fragments in registers (48 VGPRs) ----
  // B layout: lane holds col = lane&15, k = 32*s + 8*kg + j
  short8 w1b[4];
#pragma unroll
  for (int cb = 0; cb < 4; ++cb) {
    short8 t;
#pragma unroll
    for (int j = 0; j < 8; ++j) t[j] = f2bf(W1[(kg * 8 + j) * 64 + cb * 16 + row]);
    w1b[cb] = t;
  }
  short8 w2b[2][4];
#pragma unroll
  for (int s = 0; s < 2; ++s)
#pragma unroll
    for (int cb = 0; cb < 4; ++cb) {
      short8 t;
#pragma unroll
      for (int j = 0; j < 8; ++j)
        t[j] = f2bf(W2[(s * 32 + kg * 8 + j) * 64 + cb * 16 + row]);
      w2b[s][cb] = t;
    }

  __syncthreads();  // w3f table ready

  const f32x4 zero = {0.f, 0.f, 0.f, 0.f};
  const int base = (blockIdx.x * 4 + wv) * (16 * ITERS / 16) * 16;  // 256 pts/wave

  for (int it = 0; it < ITERS; ++it) {
    const int p0 = base + it * 16;
    int p = p0 + row;
    if (p > N - 1) p = N - 1;  // safety clamp (exact grid: never triggers)

    // ---- load 8 floats of this point's row ----
    const float* xr = x + p * 19;
    const int off = (kg < 2) ? 0 : (3 + (kg - 2) * 8);
    float v[8];
#pragma unroll
    for (int j = 0; j < 8; ++j) v[j] = xr[off + j];

    // ---- encode: 8 features for (point=row, k-group=kg) ----
    float e[8];
    if (kg == 0) {
      float X = v[0] * 2.f - 1.f, Y = v[1] * 2.f - 1.f, Z = v[2] * 2.f - 1.f;
      e[0] = 0.28209479177387814f;
      e[1] = -0.48860251190291987f * Y;
      e[2] = 0.48860251190291987f * Z;
      e[3] = -0.48860251190291987f * X;
      e[4] = 1.0925484305920792f * X * Y;
      e[5] = -1.0925484305920792f * Y * Z;
      e[6] = 0.94617469575756f * Z * Z - 0.31539156525252f;
      e[7] = -1.0925484305920792f * X * Z;
    } else if (kg == 1) {
      float X = v[0] * 2.f - 1.f, Y = v[1] * 2.f - 1.f, Z = v[2] * 2.f - 1.f;
      float X2 = X * X, Y2 = Y * Y, Z2 = Z * Z;
      e[0] = 0.5462742152960396f * (X2 - Y2);
      e[1] = 0.5900435899266435f * Y * (-3.f * X2 + Y2);
      e[2] = 2.890611442640554f * X * Y * Z;
      e[3] = 0.4570457994644657f * Y * (1.f - 5.f * Z2);
      e[4] = 0.3731763325901154f * Z * (5.f * Z2 - 3.f);
      e[5] = 0.4570457994644657f * X * (1.f - 5.f * Z2);
      e[6] = 1.445305721320277f * Z * (X2 - Y2);
      e[7] = 0.5900435899266435f * X * (X2 - 3.f * Y2);
    } else {
#pragma unroll
      for (int j = 0; j < 8; ++j) e[j] = v[j];
    }
    short8 a0;
#pragma unroll
    for (int j = 0; j < 8; ++j) a0[j] = f2bf(e[j]);

    // ---- layer 1: enc(16x32) @ W1(32x64) ----
    f32x4 c1[4];
#pragma unroll
    for (int cb = 0; cb < 4; ++cb) c1[cb] = MFMA16(a0, w1b[cb], zero);

    // relu -> h1 LDS (C layout: row = 4*kg + r, col = cb*16 + (lane&15))
#pragma unroll
    for (int cb = 0; cb < 4; ++cb)
#pragma unroll
      for (int r = 0; r < 4; ++r)
        h1s[wv][kg * 4 + r][cb * 16 + row] = f2bf(fmaxf(c1[cb][r], 0.f));
    __syncthreads();

    // A-fragments of h1: lane reads h1[row][32*s + 8*kg .. +8]
    short8 a1[2];
#pragma unroll
    for (int s = 0; s < 2; ++s) {
      short4v lo = *(const short4v*)&h1s[wv][row][s * 32 + kg * 8];
      short4v hi = *(const short4v*)&h1s[wv][row][s * 32 + kg * 8 + 4];
      a1[s] = __builtin_shufflevector(lo, hi, 0, 1, 2, 3, 4, 5, 6, 7);
    }

    // ---- layer 2: h1(16x64) @ W2(64x64) ----
    f32x4 c2[4];
#pragma unroll
    for (int cb = 0; cb < 4; ++cb) {
      f32x4 acc = MFMA16(a1[0], w2b[0][cb], zero);
      c2[cb] = MFMA16(a1[1], w2b[1][cb], acc);
    }

    // relu -> h2 LDS
#pragma unroll
    for (int cb = 0; cb < 4; ++cb)
#pragma unroll
      for (int r = 0; r < 4; ++r)
        h2s[wv][kg * 4 + r][cb * 16 + row] = f2bf(fmaxf(c2[cb][r], 0.f));
    __syncthreads();

    short8 a2[2];
#pragma unroll
    for (int s = 0; s < 2; ++s) {
      short4v lo = *(const short4v*)&h2s[wv][row][s * 32 + kg * 8];
      short4v hi = *(const short4v*)&h2s[wv][row][s * 32 + kg * 8 + 4];
      a2[s] = __builtin_shufflevector(lo, hi, 0, 1, 2, 3, 4, 5, 6, 7);
    }

    // ---- layer 3: h2(16x64) @ W3(64x16 padded) ----
    // W3 fragment re-read from LDS each iter (opaque ptr defeats LICM so
    // it does NOT occupy 8 persistent VGPRs).
    const short* wp = &w3f[lane][0];
    asm("" : "+v"(wp));  // compiler may not assume loop-invariance
    short8 w3lo = *(const short8*)(wp);
    short8 w3hi = *(const short8*)(wp + 8);
    f32x4 c3 = MFMA16(a2[0], w3lo, zero);
    c3 = MFMA16(a2[1], w3hi, c3);

    // store: C col (= lane&15) < 3 are the real channels; row = 4*kg + r
    if (row < 3) {
#pragma unroll
      for (int r = 0; r < 4; ++r) {
        const int q = p0 + kg * 4 + r;
        if (q < N) out[q * 3 + row] = c3[r];
      }
    }
  }
}

extern "C" void kernel_launch(void* const* d_in, const int* in_sizes, int n_in,
                              void* d_out, int out_size, void* d_ws, size_t ws_size,
                              hipStream_t stream) {
  (void)d_ws; (void)ws_size; (void)n_in; (void)out_size;
  const float* x = (const float*)d_in[0];
  const float* W1 = (const float*)d_in[1];
  const float* W2 = (const float*)d_in[2];
  const float* W3 = (const float*)d_in[3];
  float* out = (float*)d_out;
  const int N = in_sizes[0] / 19;            // 2,097,152
  const int ppb = 4 * 16 * ITERS;            // 1024 points per block
  const int blocks = (N + ppb - 1) / ppb;    // 2048
  fused_color_mlp<<<blocks, 256, 0, stream>>>(x, W1, W2, W3, out, N);
}

// Round 10
// 245.669 us; speedup vs baseline: 1.5326x; 1.5326x over previous
//
#include <hip/hip_runtime.h>
#include <hip/hip_bf16.h>

// FusedColorMLP: out = relu(relu(enc @ W1) @ W2) @ W3
// enc = [SH-deg4(x[:, :3]) (16) | x[:, 3:19] (16)]  -> 32 features
// bf16 MFMA (16x16x32), fp32 accumulate.
// R10: widen to 2 independent 16-point tiles per iteration (pure
// replication of the R7-proven tile). Halves barriers per point and
// doubles ILP in every phase. R9 post-mortem: forcing occupancy (256,8)
// spilled the 56 weight VGPRs (FETCH 78->475MB) -- occupancy is NOT the
// binding constraint (79% occ was 2x slower). R7 remains the base:
// latency-bound serial chain (~2100 cyc/iter vs ~600 issue).
// __launch_bounds__(256,4): cap at the 128-VGPR quantum, ample margin.

typedef short short8 __attribute__((ext_vector_type(8)));
typedef short short4v __attribute__((ext_vector_type(4)));
typedef float f32x4 __attribute__((ext_vector_type(4)));

#define MFMA16(a, b, c) __builtin_amdgcn_mfma_f32_16x16x32_bf16((a), (b), (c), 0, 0, 0)

static __device__ __forceinline__ short f2bf(float f) {
  __hip_bfloat16 h = __float2bfloat16(f);  // RNE
  return __builtin_bit_cast(short, h);
}

#define LDS_PAD 68   // row stride in bf16 elems: 136B (2-way bank alias: free)
#define ITERS 8      // 2 tiles x 16 pts x 8 iters = 256 pts per wave

__global__ __launch_bounds__(256, 4) void fused_color_mlp(
    const float* __restrict__ x, const float* __restrict__ W1,
    const float* __restrict__ W2, const float* __restrict__ W3,
    float* __restrict__ out, int N) {
  __shared__ short h1s[4][2][16][LDS_PAD];
  __shared__ short h2s[4][2][16][LDS_PAD];

  const int tid = threadIdx.x;
  const int wv = tid >> 6;      // wave in block
  const int lane = tid & 63;
  const int row = lane & 15;    // A row / B,C col
  const int kg = lane >> 4;     // k-group (8 consecutive k per lane)

  // ---- one-time: weight B-fragments in registers (56 VGPRs) ----
  // B layout: lane holds col = lane&15, k = 32*s + 8*kg + j
  short8 w1b[4];
#pragma unroll
  for (int cb = 0; cb < 4; ++cb) {
    short8 t;
#pragma unroll
    for (int j = 0; j < 8; ++j) t[j] = f2bf(W1[(kg * 8 + j) * 64 + cb * 16 + row]);
    w1b[cb] = t;
  }
  short8 w2b[2][4];
#pragma unroll
  for (int s = 0; s < 2; ++s)
#pragma unroll
    for (int cb = 0; cb < 4; ++cb) {
      short8 t;
#pragma unroll
      for (int j = 0; j < 8; ++j)
        t[j] = f2bf(W2[(s * 32 + kg * 8 + j) * 64 + cb * 16 + row]);
      w2b[s][cb] = t;
    }
  // W3 (64x3) zero-padded to 16 cols; clamped index: speculation-safe.
  short8 w3b[2];
  const int c3r = (row < 3) ? row : 2;
#pragma unroll
  for (int s = 0; s < 2; ++s) {
    short8 t;
#pragma unroll
    for (int j = 0; j < 8; ++j) {
      short w = f2bf(W3[(s * 32 + kg * 8 + j) * 3 + c3r]);
      t[j] = (row < 3) ? w : (short)0;
    }
    w3b[s] = t;
  }

  const f32x4 zero = {0.f, 0.f, 0.f, 0.f};
  const int base = (blockIdx.x * 4 + wv) * (32 * ITERS);  // 256 pts/wave

  for (int it = 0; it < ITERS; ++it) {
    const int p0 = base + it * 32;   // tile tt covers p0+16*tt .. +15

    // ---- phase 1: load 2x8 floats (16 loads in flight together) ----
    float v[2][8];
#pragma unroll
    for (int tt = 0; tt < 2; ++tt) {
      int p = p0 + tt * 16 + row;
      if (p > N - 1) p = N - 1;  // safety clamp (exact grid: no trigger)
      const float* xr = x + (long long)p * 19;
      const int off = (kg < 2) ? 0 : (3 + (kg - 2) * 8);
#pragma unroll
      for (int j = 0; j < 8; ++j) v[tt][j] = xr[off + j];
    }

    // ---- phase 2: encode both tiles ----
    short8 a0[2];
#pragma unroll
    for (int tt = 0; tt < 2; ++tt) {
      float e[8];
      if (kg == 0) {
        float X = v[tt][0] * 2.f - 1.f, Y = v[tt][1] * 2.f - 1.f, Z = v[tt][2] * 2.f - 1.f;
        e[0] = 0.28209479177387814f;
        e[1] = -0.48860251190291987f * Y;
        e[2] = 0.48860251190291987f * Z;
        e[3] = -0.48860251190291987f * X;
        e[4] = 1.0925484305920792f * X * Y;
        e[5] = -1.0925484305920792f * Y * Z;
        e[6] = 0.94617469575756f * Z * Z - 0.31539156525252f;
        e[7] = -1.0925484305920792f * X * Z;
      } else if (kg == 1) {
        float X = v[tt][0] * 2.f - 1.f, Y = v[tt][1] * 2.f - 1.f, Z = v[tt][2] * 2.f - 1.f;
        float X2 = X * X, Y2 = Y * Y, Z2 = Z * Z;
        e[0] = 0.5462742152960396f * (X2 - Y2);
        e[1] = 0.5900435899266435f * Y * (-3.f * X2 + Y2);
        e[2] = 2.890611442640554f * X * Y * Z;
        e[3] = 0.4570457994644657f * Y * (1.f - 5.f * Z2);
        e[4] = 0.3731763325901154f * Z * (5.f * Z2 - 3.f);
        e[5] = 0.4570457994644657f * X * (1.f - 5.f * Z2);
        e[6] = 1.445305721320277f * Z * (X2 - Y2);
        e[7] = 0.5900435899266435f * X * (X2 - 3.f * Y2);
      } else {
#pragma unroll
        for (int j = 0; j < 8; ++j) e[j] = v[tt][j];
      }
#pragma unroll
      for (int j = 0; j < 8; ++j) a0[tt][j] = f2bf(e[j]);
    }

    // ---- layer 1: enc(16x32) @ W1(32x64), both tiles ----
    f32x4 c1[2][4];
#pragma unroll
    for (int tt = 0; tt < 2; ++tt)
#pragma unroll
      for (int cb = 0; cb < 4; ++cb) c1[tt][cb] = MFMA16(a0[tt], w1b[cb], zero);

    // relu -> h1 LDS (C layout: row = 4*kg + r, col = cb*16 + (lane&15))
#pragma unroll
    for (int tt = 0; tt < 2; ++tt)
#pragma unroll
      for (int cb = 0; cb < 4; ++cb)
#pragma unroll
        for (int r = 0; r < 4; ++r)
          h1s[wv][tt][kg * 4 + r][cb * 16 + row] = f2bf(fmaxf(c1[tt][cb][r], 0.f));
    __syncthreads();

    // A-fragments of h1: lane reads h1[row][32*s + 8*kg .. +8]
    short8 a1[2][2];
#pragma unroll
    for (int tt = 0; tt < 2; ++tt)
#pragma unroll
      for (int s = 0; s < 2; ++s) {
        short4v lo = *(const short4v*)&h1s[wv][tt][row][s * 32 + kg * 8];
        short4v hi = *(const short4v*)&h1s[wv][tt][row][s * 32 + kg * 8 + 4];
        a1[tt][s] = __builtin_shufflevector(lo, hi, 0, 1, 2, 3, 4, 5, 6, 7);
      }

    // ---- layer 2: h1(16x64) @ W2(64x64), both tiles ----
    f32x4 c2[2][4];
#pragma unroll
    for (int tt = 0; tt < 2; ++tt)
#pragma unroll
      for (int cb = 0; cb < 4; ++cb) {
        f32x4 acc = MFMA16(a1[tt][0], w2b[0][cb], zero);
        c2[tt][cb] = MFMA16(a1[tt][1], w2b[1][cb], acc);
      }

    // relu -> h2 LDS
#pragma unroll
    for (int tt = 0; tt < 2; ++tt)
#pragma unroll
      for (int cb = 0; cb < 4; ++cb)
#pragma unroll
        for (int r = 0; r < 4; ++r)
          h2s[wv][tt][kg * 4 + r][cb * 16 + row] = f2bf(fmaxf(c2[tt][cb][r], 0.f));
    __syncthreads();

    short8 a2[2][2];
#pragma unroll
    for (int tt = 0; tt < 2; ++tt)
#pragma unroll
      for (int s = 0; s < 2; ++s) {
        short4v lo = *(const short4v*)&h2s[wv][tt][row][s * 32 + kg * 8];
        short4v hi = *(const short4v*)&h2s[wv][tt][row][s * 32 + kg * 8 + 4];
        a2[tt][s] = __builtin_shufflevector(lo, hi, 0, 1, 2, 3, 4, 5, 6, 7);
      }

    // ---- layer 3 + store, both tiles ----
#pragma unroll
    for (int tt = 0; tt < 2; ++tt) {
      f32x4 c3 = MFMA16(a2[tt][0], w3b[0], zero);
      c3 = MFMA16(a2[tt][1], w3b[1], c3);
      if (row < 3) {
#pragma unroll
        for (int r = 0; r < 4; ++r) {
          const int q = p0 + tt * 16 + kg * 4 + r;
          if (q < N) out[(long long)q * 3 + row] = c3[r];
        }
      }
    }
  }
}

extern "C" void kernel_launch(void* const* d_in, const int* in_sizes, int n_in,
                              void* d_out, int out_size, void* d_ws, size_t ws_size,
                              hipStream_t stream) {
  (void)d_ws; (void)ws_size; (void)n_in; (void)out_size;
  const float* x = (const float*)d_in[0];
  const float* W1 = (const float*)d_in[1];
  const float* W2 = (const float*)d_in[2];
  const float* W3 = (const float*)d_in[3];
  float* out = (float*)d_out;
  const int N = in_sizes[0] / 19;            // 2,097,152
  const int ppb = 4 * 32 * ITERS;            // 1024 points per block
  const int blocks = (N + ppb - 1) / ppb;    // 2048
  fused_color_mlp<<<blocks, 256, 0, stream>>>(x, W1, W2, W3, out, N);
}